// Round 8
// baseline (286.617 us; speedup 1.0000x reference)
//
#include <hip/hip_runtime.h>
#include <cstdint>
#include <type_traits>

#define BATCH  2
#define SEQ    2048
#define DM     1024
#define NH     16
#define DH     64
#define MR     (BATCH*SEQ)   // 4096 rows

typedef float  f32x4  __attribute__((ext_vector_type(4)));
typedef short  s16x8  __attribute__((ext_vector_type(8)));
typedef unsigned short u16x4 __attribute__((ext_vector_type(4)));
typedef unsigned short u16x8 __attribute__((ext_vector_type(8)));
typedef __bf16 bf16x8 __attribute__((ext_vector_type(8)));

// ---- mfma arg-type detection: accept whichever signature this clang has ----
template <typename V, typename = void> struct mfma_ok : std::false_type {};
template <typename V>
struct mfma_ok<V, std::void_t<decltype(__builtin_amdgcn_mfma_f32_16x16x32_bf16(
    std::declval<V>(), std::declval<V>(), std::declval<f32x4>(), 0, 0, 0))>>
    : std::true_type {};
using frag_t = std::conditional_t<mfma_ok<bf16x8>::value, bf16x8, s16x8>;
static_assert(mfma_ok<frag_t>::value, "no usable mfma bf16 fragment type");

template <typename V>
__device__ inline f32x4 mfma_16x16x32_bf16(V a, V b, f32x4 c) {
  return __builtin_amdgcn_mfma_f32_16x16x32_bf16(a, b, c, 0, 0, 0);
}

__device__ inline uint16_t f2b(float f) {   // RNE f32 -> bf16 bits
  union { float f; uint32_t u; } v; v.f = f;
  return (uint16_t)((v.u + 0x7fffu + ((v.u >> 16) & 1u)) >> 16);
}

// async global->LDS, 16 B per lane; LDS dest = wave-uniform base + lane*16
__device__ __forceinline__ void ld_lds16(const uint16_t* g, uint16_t* l) {
  __builtin_amdgcn_global_load_lds(
      (const __attribute__((address_space(1))) uint32_t*)g,
      (__attribute__((address_space(3))) uint32_t*)l, 16, 0, 0);
}

// ------- fused prep: weight transpose (blocks 0..4095) + x cast (rest) -------
// transpose: W[k][n] fp32 -> WT[n][k] bf16, 32x32 tiles.
// prep_x: x fp32 -> bf16, 2048 elems/block.
__global__ __launch_bounds__(256) void prep_all(
    const float* __restrict__ w0, const float* __restrict__ w1,
    const float* __restrict__ w2, const float* __restrict__ w3,
    uint16_t* __restrict__ wtout,
    const float* __restrict__ x, uint16_t* __restrict__ xb)
{
  const int bid = blockIdx.x;
  const int t = threadIdx.x;
  if (bid < 4096) {
    __shared__ uint16_t tile[32][33];
    const int z = bid >> 10, rem = bid & 1023;
    const int by = rem >> 5, bx = rem & 31;
    const int tx = t & 31, ty = t >> 5;
    const float* W = z == 0 ? w0 : z == 1 ? w1 : z == 2 ? w2 : w3;
    uint16_t* WT = wtout + (size_t)z * DM * DM;
    const int n  = bx * 32 + tx;
    const int k0 = by * 32;
    for (int i = ty; i < 32; i += 8)
      tile[i][tx] = f2b(W[(size_t)(k0 + i) * DM + n]);
    __syncthreads();
    const int k = k0 + tx;
    const int nb = bx * 32;
    for (int i = ty; i < 32; i += 8)
      WT[(size_t)(nb + i) * DM + k] = tile[tx][i];
  } else {
    const size_t i0 = ((size_t)(bid - 4096) * 256 + t) * 8;
    f32x4 a = *(const f32x4*)(x + i0);
    f32x4 b = *(const f32x4*)(x + i0 + 4);
    u16x8 o = {f2b(a[0]), f2b(a[1]), f2b(a[2]), f2b(a[3]),
               f2b(b[0]), f2b(b[1]), f2b(b[2]), f2b(b[3])};
    *(u16x8*)(xb + i0) = o;
  }
}

// ---------------- GEMM: C[M,1024] = A[M,1024] @ WT^T + bias ----------------
// 128x128 tile, BK=32, 4 waves each 64x64 as 4x4 mfma_f32_16x16x32_bf16.
// Staging via global_load_lds (16 B/lane, async DMA). LDS unpadded with XOR
// swizzle: 16B slot(row,kc) = row*4 + (kc ^ ((row>>1)&3)).
// F32OUT: fp32 C-write. QKV: z0 scaled log2e/32, z2 written V^T [b][h][d][s].
template <bool F32OUT, bool QKV>
__global__ __launch_bounds__(256) void gemm_bt(
    const uint16_t* __restrict__ A,       // [MR][DM] bf16
    const uint16_t* __restrict__ WTbase,  // z-th weight at z*DM*DM, [n][k]
    const float* __restrict__ bias0, const float* __restrict__ bias1,
    const float* __restrict__ bias2,
    void* __restrict__ o0, void* __restrict__ o1, void* __restrict__ o2)
{
  const int z = blockIdx.z;
  const uint16_t* WT   = WTbase + (size_t)z * DM * DM;
  const float*    bias = z == 0 ? bias0 : z == 1 ? bias1 : bias2;
  void*           Cout = z == 0 ? o0 : z == 1 ? o1 : o2;
  // log2e/32: attention uses exp2, so fold log2(e) into the Q scale
  const float     sc   = (QKV && z == 0) ? 0.045084219f : 1.0f;

  __shared__ __align__(16) uint16_t Al[128 * 32];   // 8 KB, swizzled
  __shared__ __align__(16) uint16_t Bl[128 * 32];

  const int m0 = blockIdx.y * 128, n0 = blockIdx.x * 128;
  const int t = threadIdx.x;
  const int lane = t & 63, w = t >> 6;
  const int l15 = lane & 15, quad = lane >> 4;
  const int wm = (w >> 1) * 64, wn = (w & 1) * 64;

  const uint16_t* gA[2];
  const uint16_t* gB[2];
  uint16_t* lA[2];
  uint16_t* lB[2];
#pragma unroll
  for (int i = 0; i < 2; i++) {
    const int S = (w * 2 + i) * 64 + lane;
    const int row = S >> 2;
    const int kc  = (S & 3) ^ ((row >> 1) & 3);
    gA[i] = A  + (size_t)(m0 + row) * DM + kc * 8;
    gB[i] = WT + (size_t)(n0 + row) * DM + kc * 8;
    lA[i] = &Al[(w * 2 + i) * 512];
    lB[i] = &Bl[(w * 2 + i) * 512];
  }

  int offA[4], offB[4];
#pragma unroll
  for (int i = 0; i < 4; i++) {
    const int ra = wm + i * 16 + l15;
    offA[i] = (ra * 4 + (quad ^ ((ra >> 1) & 3))) * 8;
    const int rb = wn + i * 16 + l15;
    offB[i] = (rb * 4 + (quad ^ ((rb >> 1) & 3))) * 8;
  }

  f32x4 acc[4][4];
#pragma unroll
  for (int i = 0; i < 4; i++)
#pragma unroll
    for (int j = 0; j < 4; j++) acc[i][j] = {0.f, 0.f, 0.f, 0.f};

  for (int k0 = 0; k0 < DM; k0 += 32) {
    __syncthreads();
    ld_lds16(gA[0] + k0, lA[0]);
    ld_lds16(gA[1] + k0, lA[1]);
    ld_lds16(gB[0] + k0, lB[0]);
    ld_lds16(gB[1] + k0, lB[1]);
    __syncthreads();
    frag_t af[4], bf[4];
#pragma unroll
    for (int i = 0; i < 4; i++) af[i] = *(const frag_t*)&Al[offA[i]];
#pragma unroll
    for (int j = 0; j < 4; j++) bf[j] = *(const frag_t*)&Bl[offB[j]];
#pragma unroll
    for (int i = 0; i < 4; i++)
#pragma unroll
      for (int j = 0; j < 4; j++)
        acc[i][j] = mfma_16x16x32_bf16(af[i], bf[j], acc[i][j]);
  }

  // epilogue: C/D layout col=lane&15, row=quad*4+reg (verified m89/m91)
#pragma unroll
  for (int j = 0; j < 4; j++) {
    const int col = n0 + wn + j * 16 + l15;
    const float bv = bias[col];
#pragma unroll
    for (int i = 0; i < 4; i++) {
      const int row = m0 + wm + i * 16 + quad * 4;
      if (QKV && z == 2) {
        const int bb = row >> 11, s = row & 2047;
        const int hh = col >> 6,  dd = col & 63;
        u16x4 pk = {f2b(acc[i][j][0] + bv), f2b(acc[i][j][1] + bv),
                    f2b(acc[i][j][2] + bv), f2b(acc[i][j][3] + bv)};
        *(u16x4*)((uint16_t*)Cout +
                  (((size_t)bb * NH + hh) * DH + dd) * SEQ + s) = pk;
      } else {
#pragma unroll
        for (int r = 0; r < 4; r++) {
          const float val = (acc[i][j][r] + bv) * sc;
          if (F32OUT)
            ((float*)Cout)[(size_t)(row + r) * DM + col] = val;
          else
            ((uint16_t*)Cout)[(size_t)(row + r) * DM + col] = f2b(val);
        }
      }
    }
  }
}

// ---------------- MFMA flash attention, causal, barrier-free ----------------
// Fixed-max softmax: s = (q*log2e/32)·k has |s| < ~2.2 => P = exp2(s) safe.
// Per-WAVE independent jobs (16 q-rows each); no __syncthreads anywhere.
// K-frags (B-layout [key][d]) and V^T-frags (B-layout [d][key]) are loaded
// straight from global (16B contiguous, L1/L2 multicast). Only LDS use is
// the per-wave P C-layout->A-layout round-trip.
// Job balance: block b waves take jobs {2b, 2b+1, 4095-2b, 4094-2b};
// job j: win = 127 - (j>>5), bh = j&31 => every block does exactly 66 tiles.
__global__ __launch_bounds__(256, 4) void attn_mfma(
    const uint16_t* __restrict__ Q,   // [MR][DM] (pre-scaled by log2e/32)
    const uint16_t* __restrict__ K,   // [MR][DM]
    const uint16_t* __restrict__ Vt,  // [B*NH][DH][SEQ]
    uint16_t* __restrict__ O)         // [MR][DM] (may alias Q)
{
  __shared__ __align__(16) uint16_t Pl[4 * 16 * 72];

  const int t = threadIdx.x;
  const int lane = t & 63, wave = t >> 6;
  const int l15 = lane & 15, quad = lane >> 4;

  const int bb = blockIdx.x;
  const int j = (wave < 2) ? (2 * bb + wave) : (4095 - 2 * bb - (wave - 2));
  const int win = 127 - (j >> 5);
  const int bh  = j & 31;
  const int b = bh >> 4, h = bh & 15;
  const int q0 = win * 16;
  const int nkt = (win >> 2) + 1;

  // Q fragments (A-layout): rows q0+l15, k = ks*32+quad*8
  frag_t qf[2];
  const uint16_t* qbase = Q + (size_t)(b * SEQ + q0) * DM + h * DH;
#pragma unroll
  for (int ks = 0; ks < 2; ks++)
    qf[ks] = *(const frag_t*)(qbase + (size_t)l15 * DM + ks * 32 + quad * 8);

  f32x4 Oacc[4];
#pragma unroll
  for (int dt = 0; dt < 4; dt++) Oacc[dt] = {0.f, 0.f, 0.f, 0.f};
  float lsum[4] = {0.f, 0.f, 0.f, 0.f};

  const uint16_t* Kg = K  + (size_t)(b * SEQ) * DM + h * DH;
  const uint16_t* Vg = Vt + (size_t)bh * DH * SEQ;
  uint16_t* Pw = Pl + wave * 16 * 72;

  for (int kt = 0; kt < nkt; kt++) {
    // ---- S = Q K^T; K frags direct from global (B-layout, 16B contig) ----
    f32x4 S[4];
#pragma unroll
    for (int nt = 0; nt < 4; nt++) S[nt] = {0.f, 0.f, 0.f, 0.f};
#pragma unroll
    for (int ks = 0; ks < 2; ks++) {
      frag_t bf[4];
#pragma unroll
      for (int nt = 0; nt < 4; nt++)
        bf[nt] = *(const frag_t*)(Kg +
                 (size_t)(kt * 64 + nt * 16 + l15) * DM + ks * 32 + quad * 8);
#pragma unroll
      for (int nt = 0; nt < 4; nt++)
        S[nt] = mfma_16x16x32_bf16(qf[ks], bf[nt], S[nt]);
    }

    // ---- P = exp2(S) (causal-masked -> 0), row-sum in regs, P -> LDS ----
    const bool diag = (kt == nkt - 1);
#pragma unroll
    for (int r = 0; r < 4; r++) {
      const int row = q0 + quad * 4 + r;
#pragma unroll
      for (int nt = 0; nt < 4; nt++) {
        const int col = kt * 64 + nt * 16 + l15;
        float p = exp2f(S[nt][r]);
        if (diag && col > row) p = 0.f;
        lsum[r] += p;
        Pw[(quad * 4 + r) * 72 + nt * 16 + l15] = f2b(p);
      }
    }

    // ---- O += P V; V^T frags direct from global (B-layout, 16B contig) ----
#pragma unroll
    for (int ks = 0; ks < 2; ks++) {
      frag_t pf = *(const frag_t*)&Pw[l15 * 72 + ks * 32 + quad * 8];
      frag_t vf[4];
#pragma unroll
      for (int dt = 0; dt < 4; dt++)
        vf[dt] = *(const frag_t*)(Vg +
                 (size_t)(dt * 16 + l15) * SEQ + kt * 64 + ks * 32 + quad * 8);
#pragma unroll
      for (int dt = 0; dt < 4; dt++)
        Oacc[dt] = mfma_16x16x32_bf16(pf, vf[dt], Oacc[dt]);
    }
  }

  // ---- one-time l reduction over the 16-lane row groups ----
  float linv[4];
#pragma unroll
  for (int r = 0; r < 4; r++) {
    float l = lsum[r];
    l += __shfl_xor(l, 1);
    l += __shfl_xor(l, 2);
    l += __shfl_xor(l, 4);
    l += __shfl_xor(l, 8);
    linv[r] = 1.f / l;
  }

  // ---- epilogue: O /= l, write (C-layout) ----
  uint16_t* obase = O + (size_t)(b * SEQ + q0) * DM + h * DH;
#pragma unroll
  for (int r = 0; r < 4; r++) {
    const int row = quad * 4 + r;
#pragma unroll
    for (int dt = 0; dt < 4; dt++)
      obase[(size_t)row * DM + dt * 16 + l15] = f2b(Oacc[dt][r] * linv[r]);
  }
}

// ---------------- launch ----------------
// ws: WT (8 MB) + Qb (8 MB) + Kb (8 MB) = 24 MB.
// d_out (16 MiB fp32) double-duty: first 8 MiB = V^T (bf16), second 8 MiB =
// xb (bf16 x). Both dead before the final projection overwrites all of d_out.
// Attention output aliases Qb.
extern "C" void kernel_launch(void* const* d_in, const int* in_sizes, int n_in,
                              void* d_out, int out_size, void* d_ws, size_t ws_size,
                              hipStream_t stream) {
  const float* x  = (const float*)d_in[0];
  const float* Wq = (const float*)d_in[1];
  const float* bq = (const float*)d_in[2];
  const float* Wk = (const float*)d_in[3];
  const float* bk = (const float*)d_in[4];
  const float* Wv = (const float*)d_in[5];
  const float* bv = (const float*)d_in[6];
  const float* Wo = (const float*)d_in[7];
  const float* bo = (const float*)d_in[8];

  uint16_t* WT = (uint16_t*)d_ws;
  uint16_t* Qb = WT + (size_t)4 * DM * DM;
  uint16_t* Kb = Qb + (size_t)MR * DM;
  uint16_t* Vtb = (uint16_t*)d_out;                   // V^T [B*NH][DH][SEQ]
  uint16_t* xb  = (uint16_t*)d_out + (size_t)MR * DM; // bf16 x, upper 8 MiB

  prep_all<<<dim3(4096 + MR * DM / 2048), 256, 0, stream>>>(
      Wq, Wk, Wv, Wo, WT, x, xb);
  gemm_bt<false, true><<<dim3(8, 32, 3), 256, 0, stream>>>(
      xb, WT, bq, bk, bv, Qb, Kb, Vtb);
  attn_mfma<<<dim3(1024), 256, 0, stream>>>(Qb, Kb, Vtb, Qb);
  gemm_bt<true, false><<<dim3(8, 32, 1), 256, 0, stream>>>(
      Qb, WT + (size_t)3 * DM * DM, bo, bo, bo, d_out, d_out, d_out);
}

// Round 9
// 218.517 us; speedup vs baseline: 1.3116x; 1.3116x over previous
//
#include <hip/hip_runtime.h>
#include <cstdint>
#include <type_traits>

#define BATCH  2
#define SEQ    2048
#define DM     1024
#define NH     16
#define DH     64
#define MR     (BATCH*SEQ)   // 4096 rows

typedef float  f32x4  __attribute__((ext_vector_type(4)));
typedef short  s16x8  __attribute__((ext_vector_type(8)));
typedef unsigned short u16x4 __attribute__((ext_vector_type(4)));
typedef unsigned short u16x8 __attribute__((ext_vector_type(8)));
typedef __bf16 bf16x8 __attribute__((ext_vector_type(8)));

// ---- mfma arg-type detection: accept whichever signature this clang has ----
template <typename V, typename = void> struct mfma_ok : std::false_type {};
template <typename V>
struct mfma_ok<V, std::void_t<decltype(__builtin_amdgcn_mfma_f32_16x16x32_bf16(
    std::declval<V>(), std::declval<V>(), std::declval<f32x4>(), 0, 0, 0))>>
    : std::true_type {};
using frag_t = std::conditional_t<mfma_ok<bf16x8>::value, bf16x8, s16x8>;
static_assert(mfma_ok<frag_t>::value, "no usable mfma bf16 fragment type");

template <typename V>
__device__ inline f32x4 mfma_16x16x32_bf16(V a, V b, f32x4 c) {
  return __builtin_amdgcn_mfma_f32_16x16x32_bf16(a, b, c, 0, 0, 0);
}

__device__ inline uint16_t f2b(float f) {   // RNE f32 -> bf16 bits
  union { float f; uint32_t u; } v; v.f = f;
  return (uint16_t)((v.u + 0x7fffu + ((v.u >> 16) & 1u)) >> 16);
}

// async global->LDS, 16 B per lane; LDS dest = wave-uniform base + lane*16
__device__ __forceinline__ void ld_lds16(const uint16_t* g, uint16_t* l) {
  __builtin_amdgcn_global_load_lds(
      (const __attribute__((address_space(1))) uint32_t*)g,
      (__attribute__((address_space(3))) uint32_t*)l, 16, 0, 0);
}

// ------- fused prep: weight transpose (blocks 0..4095) + x cast (rest) -------
__global__ __launch_bounds__(256) void prep_all(
    const float* __restrict__ w0, const float* __restrict__ w1,
    const float* __restrict__ w2, const float* __restrict__ w3,
    uint16_t* __restrict__ wtout,
    const float* __restrict__ x, uint16_t* __restrict__ xb)
{
  const int bid = blockIdx.x;
  const int t = threadIdx.x;
  if (bid < 4096) {
    __shared__ uint16_t tile[32][33];
    const int z = bid >> 10, rem = bid & 1023;
    const int by = rem >> 5, bx = rem & 31;
    const int tx = t & 31, ty = t >> 5;
    const float* W = z == 0 ? w0 : z == 1 ? w1 : z == 2 ? w2 : w3;
    uint16_t* WT = wtout + (size_t)z * DM * DM;
    const int n  = bx * 32 + tx;
    const int k0 = by * 32;
    for (int i = ty; i < 32; i += 8)
      tile[i][tx] = f2b(W[(size_t)(k0 + i) * DM + n]);
    __syncthreads();
    const int k = k0 + tx;
    const int nb = bx * 32;
    for (int i = ty; i < 32; i += 8)
      WT[(size_t)(nb + i) * DM + k] = tile[tx][i];
  } else {
    const size_t i0 = ((size_t)(bid - 4096) * 256 + t) * 8;
    f32x4 a = *(const f32x4*)(x + i0);
    f32x4 b = *(const f32x4*)(x + i0 + 4);
    u16x8 o = {f2b(a[0]), f2b(a[1]), f2b(a[2]), f2b(a[3]),
               f2b(b[0]), f2b(b[1]), f2b(b[2]), f2b(b[3])};
    *(u16x8*)(xb + i0) = o;
  }
}

// ---------------- GEMM: C[M,1024] = A[M,1024] @ WT^T + bias ----------------
// 128x128 tile, BK=32, 4 waves each 64x64 as 4x4 mfma_f32_16x16x32_bf16.
// Staging via global_load_lds (16 B/lane, async DMA). LDS unpadded with XOR
// swizzle: 16B slot(row,kc) = row*4 + (kc ^ ((row>>1)&3)).
// F32OUT: fp32 C-write. QKV: z0 scaled log2e/32, z2 written V^T [b][h][d][s].
template <bool F32OUT, bool QKV>
__global__ __launch_bounds__(256) void gemm_bt(
    const uint16_t* __restrict__ A,       // [MR][DM] bf16
    const uint16_t* __restrict__ WTbase,  // z-th weight at z*DM*DM, [n][k]
    const float* __restrict__ bias0, const float* __restrict__ bias1,
    const float* __restrict__ bias2,
    void* __restrict__ o0, void* __restrict__ o1, void* __restrict__ o2)
{
  const int z = blockIdx.z;
  const uint16_t* WT   = WTbase + (size_t)z * DM * DM;
  const float*    bias = z == 0 ? bias0 : z == 1 ? bias1 : bias2;
  void*           Cout = z == 0 ? o0 : z == 1 ? o1 : o2;
  // log2e/32: attention uses exp2, so fold log2(e) into the Q scale
  const float     sc   = (QKV && z == 0) ? 0.045084219f : 1.0f;

  __shared__ __align__(16) uint16_t Al[128 * 32];   // 8 KB, swizzled
  __shared__ __align__(16) uint16_t Bl[128 * 32];

  const int m0 = blockIdx.y * 128, n0 = blockIdx.x * 128;
  const int t = threadIdx.x;
  const int lane = t & 63, w = t >> 6;
  const int l15 = lane & 15, quad = lane >> 4;
  const int wm = (w >> 1) * 64, wn = (w & 1) * 64;

  const uint16_t* gA[2];
  const uint16_t* gB[2];
  uint16_t* lA[2];
  uint16_t* lB[2];
#pragma unroll
  for (int i = 0; i < 2; i++) {
    const int S = (w * 2 + i) * 64 + lane;
    const int row = S >> 2;
    const int kc  = (S & 3) ^ ((row >> 1) & 3);
    gA[i] = A  + (size_t)(m0 + row) * DM + kc * 8;
    gB[i] = WT + (size_t)(n0 + row) * DM + kc * 8;
    lA[i] = &Al[(w * 2 + i) * 512];
    lB[i] = &Bl[(w * 2 + i) * 512];
  }

  int offA[4], offB[4];
#pragma unroll
  for (int i = 0; i < 4; i++) {
    const int ra = wm + i * 16 + l15;
    offA[i] = (ra * 4 + (quad ^ ((ra >> 1) & 3))) * 8;
    const int rb = wn + i * 16 + l15;
    offB[i] = (rb * 4 + (quad ^ ((rb >> 1) & 3))) * 8;
  }

  f32x4 acc[4][4];
#pragma unroll
  for (int i = 0; i < 4; i++)
#pragma unroll
    for (int j = 0; j < 4; j++) acc[i][j] = {0.f, 0.f, 0.f, 0.f};

  for (int k0 = 0; k0 < DM; k0 += 32) {
    __syncthreads();
    ld_lds16(gA[0] + k0, lA[0]);
    ld_lds16(gA[1] + k0, lA[1]);
    ld_lds16(gB[0] + k0, lB[0]);
    ld_lds16(gB[1] + k0, lB[1]);
    __syncthreads();
    frag_t af[4], bf[4];
#pragma unroll
    for (int i = 0; i < 4; i++) af[i] = *(const frag_t*)&Al[offA[i]];
#pragma unroll
    for (int j = 0; j < 4; j++) bf[j] = *(const frag_t*)&Bl[offB[j]];
#pragma unroll
    for (int i = 0; i < 4; i++)
#pragma unroll
      for (int j = 0; j < 4; j++)
        acc[i][j] = mfma_16x16x32_bf16(af[i], bf[j], acc[i][j]);
  }

  // epilogue: C/D layout col=lane&15, row=quad*4+reg (verified m89/m91)
#pragma unroll
  for (int j = 0; j < 4; j++) {
    const int col = n0 + wn + j * 16 + l15;
    const float bv = bias[col];
#pragma unroll
    for (int i = 0; i < 4; i++) {
      const int row = m0 + wm + i * 16 + quad * 4;
      if (QKV && z == 2) {
        const int bb = row >> 11, s = row & 2047;
        const int hh = col >> 6,  dd = col & 63;
        u16x4 pk = {f2b(acc[i][j][0] + bv), f2b(acc[i][j][1] + bv),
                    f2b(acc[i][j][2] + bv), f2b(acc[i][j][3] + bv)};
        *(u16x4*)((uint16_t*)Cout +
                  (((size_t)bb * NH + hh) * DH + dd) * SEQ + s) = pk;
      } else {
#pragma unroll
        for (int r = 0; r < 4; r++) {
          const float val = (acc[i][j][r] + bv) * sc;
          if (F32OUT)
            ((float*)Cout)[(size_t)(row + r) * DM + col] = val;
          else
            ((uint16_t*)Cout)[(size_t)(row + r) * DM + col] = f2b(val);
        }
      }
    }
  }
}

// ---------------- MFMA flash attention, causal, balanced pairs ----------------
// Fixed-max softmax: s = (q*log2e/32)·k has |s| < ~2.2 => P = exp2(s) safe;
// row-sum l accumulates per-lane, single cross-lane reduction per q-tile.
// Block = one (b,h) x a PAIR of 64-row q-tiles {pr, 31-pr} processed
// sequentially => every block runs exactly 33 k-tile iterations (static
// balance; grid 512 = 2 blocks/CU, steady occupancy, no drain).
// K/V staged in LDS (coalesced, shared by 4 waves); register-prefetch
// double-buffer: tile kt+1's global loads issue before tile kt's compute.
__global__ __launch_bounds__(256) void attn_mfma(
    const uint16_t* __restrict__ Q,   // [MR][DM] (pre-scaled by log2e/32)
    const uint16_t* __restrict__ K,   // [MR][DM]
    const uint16_t* __restrict__ Vt,  // [B*NH][DH][SEQ]
    uint16_t* __restrict__ O)         // [MR][DM] (may alias Q)
{
  __shared__ __align__(16) uint16_t Kl[64 * 72];
  __shared__ __align__(16) uint16_t Vl[64 * 72];
  __shared__ __align__(16) uint16_t Pl[4 * 16 * 72];

  const int t = threadIdx.x;
  const int lane = t & 63, wave = t >> 6;
  const int l15 = lane & 15, quad = lane >> 4;
  const int pr = blockIdx.x >> 5;       // 0..15
  const int bh = blockIdx.x & 31;
  const int b = bh >> 4, h = bh & 15;

  const uint16_t* Kg = K  + (size_t)(b * SEQ) * DM + h * DH;
  const uint16_t* Vg = Vt + (size_t)bh * DH * SEQ;
  uint16_t* Pw = Pl + wave * 16 * 72;
  const int kr = t >> 2, cp = (t & 3) * 16;   // staging slot per thread

  for (int phase = 0; phase < 2; phase++) {
    const int qt = phase == 0 ? pr : 31 - pr;
    const int q0 = qt * 64;
    const int nkt = qt + 1;

    // Q fragments (A-layout): rows q0+wave*16+l15, k = ks*32+quad*8
    frag_t qf[2];
    const uint16_t* qbase =
        Q + (size_t)(b * SEQ + q0 + wave * 16) * DM + h * DH;
#pragma unroll
    for (int ks = 0; ks < 2; ks++)
      qf[ks] = *(const frag_t*)(qbase + (size_t)l15 * DM + ks * 32 + quad * 8);

    f32x4 Oacc[4];
#pragma unroll
    for (int dt = 0; dt < 4; dt++) Oacc[dt] = {0.f, 0.f, 0.f, 0.f};
    float lsum[4] = {0.f, 0.f, 0.f, 0.f};

    // prefetch tile 0 into registers
    s16x8 kreg0, kreg1, vreg0, vreg1;
    {
      const uint16_t* kg = Kg + (size_t)kr * DM + cp;
      kreg0 = *(const s16x8*)(kg);
      kreg1 = *(const s16x8*)(kg + 8);
      const uint16_t* vg = Vg + (size_t)kr * SEQ + cp;
      vreg0 = *(const s16x8*)(vg);
      vreg1 = *(const s16x8*)(vg + 8);
    }

    for (int kt = 0; kt < nkt; kt++) {
      __syncthreads();   // previous tile's LDS reads complete
      *(s16x8*)&Kl[kr * 72 + cp]     = kreg0;
      *(s16x8*)&Kl[kr * 72 + cp + 8] = kreg1;
      *(s16x8*)&Vl[kr * 72 + cp]     = vreg0;
      *(s16x8*)&Vl[kr * 72 + cp + 8] = vreg1;
      __syncthreads();

      if (kt + 1 < nkt) {   // issue next tile's loads; latency hides under compute
        const uint16_t* kg = Kg + (size_t)((kt + 1) * 64 + kr) * DM + cp;
        kreg0 = *(const s16x8*)(kg);
        kreg1 = *(const s16x8*)(kg + 8);
        const uint16_t* vg = Vg + (size_t)kr * SEQ + (kt + 1) * 64 + cp;
        vreg0 = *(const s16x8*)(vg);
        vreg1 = *(const s16x8*)(vg + 8);
      }

      // ---- S = Q K^T ----
      f32x4 S[4];
#pragma unroll
      for (int nt = 0; nt < 4; nt++) S[nt] = {0.f, 0.f, 0.f, 0.f};
#pragma unroll
      for (int ks = 0; ks < 2; ks++) {
        frag_t bf[4];
#pragma unroll
        for (int nt = 0; nt < 4; nt++)
          bf[nt] = *(const frag_t*)&Kl[(nt * 16 + l15) * 72 + ks * 32 + quad * 8];
#pragma unroll
        for (int nt = 0; nt < 4; nt++)
          S[nt] = mfma_16x16x32_bf16(qf[ks], bf[nt], S[nt]);
      }

      // ---- P = exp2(S) (causal-masked -> 0), row-sum in regs ----
      const bool diag = (kt == qt);
#pragma unroll
      for (int r = 0; r < 4; r++) {
        const int row = q0 + wave * 16 + quad * 4 + r;
#pragma unroll
        for (int nt = 0; nt < 4; nt++) {
          const int col = kt * 64 + nt * 16 + l15;
          float p = exp2f(S[nt][r]);
          if (diag && col > row) p = 0.f;
          lsum[r] += p;
          Pw[(quad * 4 + r) * 72 + nt * 16 + l15] = f2b(p);
        }
      }

      // ---- O += P V  (A = P from LDS, B = Vt from LDS) ----
#pragma unroll
      for (int ks = 0; ks < 2; ks++) {
        frag_t pf = *(const frag_t*)&Pw[l15 * 72 + ks * 32 + quad * 8];
        frag_t vf[4];
#pragma unroll
        for (int dt = 0; dt < 4; dt++)
          vf[dt] = *(const frag_t*)&Vl[(dt * 16 + l15) * 72 + ks * 32 + quad * 8];
#pragma unroll
        for (int dt = 0; dt < 4; dt++)
          Oacc[dt] = mfma_16x16x32_bf16(pf, vf[dt], Oacc[dt]);
      }
    }

    // ---- l reduction over the 16-lane row groups ----
    float linv[4];
#pragma unroll
    for (int r = 0; r < 4; r++) {
      float l = lsum[r];
      l += __shfl_xor(l, 1);
      l += __shfl_xor(l, 2);
      l += __shfl_xor(l, 4);
      l += __shfl_xor(l, 8);
      linv[r] = 1.f / l;
    }

    // ---- epilogue: O /= l, write (C-layout) ----
    uint16_t* obase =
        O + (size_t)(b * SEQ + q0 + wave * 16) * DM + h * DH;
#pragma unroll
    for (int r = 0; r < 4; r++) {
      const int row = quad * 4 + r;
#pragma unroll
      for (int dt = 0; dt < 4; dt++)
        obase[(size_t)row * DM + dt * 16 + l15] = f2b(Oacc[dt][r] * linv[r]);
    }
  }
}

// ---------------- launch ----------------
// ws: WT (8 MB) + Qb (8 MB) + Kb (8 MB) = 24 MB.
// d_out (16 MiB fp32) double-duty: first 8 MiB = V^T (bf16), second 8 MiB =
// xb (bf16 x). Both dead before the final projection overwrites all of d_out.
// Attention output aliases Qb.
extern "C" void kernel_launch(void* const* d_in, const int* in_sizes, int n_in,
                              void* d_out, int out_size, void* d_ws, size_t ws_size,
                              hipStream_t stream) {
  const float* x  = (const float*)d_in[0];
  const float* Wq = (const float*)d_in[1];
  const float* bq = (const float*)d_in[2];
  const float* Wk = (const float*)d_in[3];
  const float* bk = (const float*)d_in[4];
  const float* Wv = (const float*)d_in[5];
  const float* bv = (const float*)d_in[6];
  const float* Wo = (const float*)d_in[7];
  const float* bo = (const float*)d_in[8];

  uint16_t* WT = (uint16_t*)d_ws;
  uint16_t* Qb = WT + (size_t)4 * DM * DM;
  uint16_t* Kb = Qb + (size_t)MR * DM;
  uint16_t* Vtb = (uint16_t*)d_out;                   // V^T [B*NH][DH][SEQ]
  uint16_t* xb  = (uint16_t*)d_out + (size_t)MR * DM; // bf16 x, upper 8 MiB

  prep_all<<<dim3(4096 + MR * DM / 2048), 256, 0, stream>>>(
      Wq, Wk, Wv, Wo, WT, x, xb);
  gemm_bt<false, true><<<dim3(8, 32, 3), 256, 0, stream>>>(
      xb, WT, bq, bk, bv, Qb, Kb, Vtb);
  attn_mfma<<<dim3(512), 256, 0, stream>>>(Qb, Kb, Vtb, Qb);
  gemm_bt<true, false><<<dim3(8, 32, 1), 256, 0, stream>>>(
      Qb, WT + (size_t)3 * DM * DM, bo, bo, bo, d_out, d_out, d_out);
}

// Round 10
// 195.134 us; speedup vs baseline: 1.4688x; 1.1198x over previous
//
#include <hip/hip_runtime.h>
#include <cstdint>
#include <type_traits>

#define BATCH  2
#define SEQ    2048
#define DM     1024
#define NH     16
#define DH     64
#define MR     (BATCH*SEQ)   // 4096 rows

typedef float  f32x4  __attribute__((ext_vector_type(4)));
typedef short  s16x8  __attribute__((ext_vector_type(8)));
typedef unsigned short u16x4 __attribute__((ext_vector_type(4)));
typedef unsigned short u16x8 __attribute__((ext_vector_type(8)));
typedef __bf16 bf16x8 __attribute__((ext_vector_type(8)));

// ---- mfma arg-type detection: accept whichever signature this clang has ----
template <typename V, typename = void> struct mfma_ok : std::false_type {};
template <typename V>
struct mfma_ok<V, std::void_t<decltype(__builtin_amdgcn_mfma_f32_16x16x32_bf16(
    std::declval<V>(), std::declval<V>(), std::declval<f32x4>(), 0, 0, 0))>>
    : std::true_type {};
using frag_t = std::conditional_t<mfma_ok<bf16x8>::value, bf16x8, s16x8>;
static_assert(mfma_ok<frag_t>::value, "no usable mfma bf16 fragment type");

template <typename V>
__device__ inline f32x4 mfma_16x16x32_bf16(V a, V b, f32x4 c) {
  return __builtin_amdgcn_mfma_f32_16x16x32_bf16(a, b, c, 0, 0, 0);
}

__device__ inline uint16_t f2b(float f) {   // RNE f32 -> bf16 bits
  union { float f; uint32_t u; } v; v.f = f;
  return (uint16_t)((v.u + 0x7fffu + ((v.u >> 16) & 1u)) >> 16);
}

// ------- fused prep: weight transpose 64x64 (blocks 0..1023) + x cast -------
__global__ __launch_bounds__(256) void prep_all(
    const float* __restrict__ w0, const float* __restrict__ w1,
    const float* __restrict__ w2, const float* __restrict__ w3,
    uint16_t* __restrict__ wtout,
    const float* __restrict__ x, uint16_t* __restrict__ xb)
{
  const int bid = blockIdx.x;
  const int t = threadIdx.x;
  if (bid < 1024) {
    __shared__ uint16_t tile[64][65];
    const int z = bid >> 8, rem = bid & 255;
    const int by = rem >> 4, bx = rem & 15;   // by: k-tile, bx: n-tile
    const int tx = t & 63, ty = t >> 6;
    const float* W = z == 0 ? w0 : z == 1 ? w1 : z == 2 ? w2 : w3;
    uint16_t* WT = wtout + (size_t)z * DM * DM;
    const int n0 = bx * 64, k0 = by * 64;
#pragma unroll
    for (int i = 0; i < 16; i++) {
      const int r = ty + i * 4;
      tile[r][tx] = f2b(W[(size_t)(k0 + r) * DM + n0 + tx]);
    }
    __syncthreads();
#pragma unroll
    for (int i = 0; i < 16; i++) {
      const int r = ty + i * 4;
      WT[(size_t)(n0 + r) * DM + k0 + tx] = tile[tx][r];
    }
  } else {
    const size_t i0 = ((size_t)(bid - 1024) * 256 + t) * 8;
    f32x4 a = *(const f32x4*)(x + i0);
    f32x4 b = *(const f32x4*)(x + i0 + 4);
    u16x8 o = {f2b(a[0]), f2b(a[1]), f2b(a[2]), f2b(a[3]),
               f2b(b[0]), f2b(b[1]), f2b(b[2]), f2b(b[3])};
    *(u16x8*)(xb + i0) = o;
  }
}

// ---------------- GEMM: C[M,1024] = A[M,1024] @ WT^T + bias ----------------
// MT x 128 tile, BK=32. Register-prefetch double-buffer: tile k+1's global
// loads issue right after the 2nd barrier, latency hides under tile k's MFMA.
// LDS unpadded + XOR swizzle: slot(row,kc) = row*4 + (kc ^ ((row>>1)&3)) —
// 0 bank conflicts (measured r9). F32OUT: fp32 C-write. QKV: z0 scaled
// log2e/32 (attn uses exp2), z2 written as V^T [b][h][d][s].
template <int MT, bool F32OUT, bool QKV>
__global__ __launch_bounds__(256, 4) void gemm_bt(
    const uint16_t* __restrict__ A,       // [MR][DM] bf16
    const uint16_t* __restrict__ WTbase,  // z-th weight at z*DM*DM, [n][k]
    const float* __restrict__ bias0, const float* __restrict__ bias1,
    const float* __restrict__ bias2,
    void* __restrict__ o0, void* __restrict__ o1, void* __restrict__ o2)
{
  constexpr int NA = MT / 64;    // A staging slots per thread
  constexpr int NI = MT / 32;    // A frags per wave
  const int z = blockIdx.z;
  const uint16_t* WT   = WTbase + (size_t)z * DM * DM;
  const float*    bias = z == 0 ? bias0 : z == 1 ? bias1 : bias2;
  void*           Cout = z == 0 ? o0 : z == 1 ? o1 : o2;
  const float     sc   = (QKV && z == 0) ? 0.045084219f : 1.0f;

  __shared__ __align__(16) uint16_t Al[MT * 32];
  __shared__ __align__(16) uint16_t Bl[128 * 32];

  const int m0 = blockIdx.y * MT, n0 = blockIdx.x * 128;
  const int t = threadIdx.x;
  const int lane = t & 63, w = t >> 6;
  const int l15 = lane & 15, quad = lane >> 4;
  const int wm = (w >> 1) * (MT / 2), wn = (w & 1) * 64;

  // staging addresses (global) and LDS bases
  const uint16_t* gA[NA];
  uint16_t*       lA[NA];
#pragma unroll
  for (int i = 0; i < NA; i++) {
    const int S = (w * NA + i) * 64 + lane;
    const int row = S >> 2;
    const int kc  = (S & 3) ^ ((row >> 1) & 3);
    gA[i] = A + (size_t)(m0 + row) * DM + kc * 8;
    lA[i] = &Al[S * 8];
  }
  const uint16_t* gB[2];
  uint16_t*       lB[2];
#pragma unroll
  for (int i = 0; i < 2; i++) {
    const int S = (w * 2 + i) * 64 + lane;
    const int row = S >> 2;
    const int kc  = (S & 3) ^ ((row >> 1) & 3);
    gB[i] = WT + (size_t)(n0 + row) * DM + kc * 8;
    lB[i] = &Bl[S * 8];
  }

  // frag LDS offsets (elems), constant per thread
  int offA[NI], offB[4];
#pragma unroll
  for (int i = 0; i < NI; i++) {
    const int ra = wm + i * 16 + l15;
    offA[i] = (ra * 4 + (quad ^ ((ra >> 1) & 3))) * 8;
  }
#pragma unroll
  for (int j = 0; j < 4; j++) {
    const int rb = wn + j * 16 + l15;
    offB[j] = (rb * 4 + (quad ^ ((rb >> 1) & 3))) * 8;
  }

  f32x4 acc[NI][4];
#pragma unroll
  for (int i = 0; i < NI; i++)
#pragma unroll
    for (int j = 0; j < 4; j++) acc[i][j] = {0.f, 0.f, 0.f, 0.f};

  // prefetch tile 0
  s16x8 pa[NA], pb[2];
#pragma unroll
  for (int i = 0; i < NA; i++) pa[i] = *(const s16x8*)(gA[i]);
#pragma unroll
  for (int i = 0; i < 2; i++)  pb[i] = *(const s16x8*)(gB[i]);

  for (int k0 = 0; k0 < DM; k0 += 32) {
    __syncthreads();   // previous iter's frag reads complete
#pragma unroll
    for (int i = 0; i < NA; i++) *(s16x8*)lA[i] = pa[i];
#pragma unroll
    for (int i = 0; i < 2; i++)  *(s16x8*)lB[i] = pb[i];
    __syncthreads();

    if (k0 + 32 < DM) {   // issue next tile's loads; hide under MFMA below
#pragma unroll
      for (int i = 0; i < NA; i++) pa[i] = *(const s16x8*)(gA[i] + k0 + 32);
#pragma unroll
      for (int i = 0; i < 2; i++)  pb[i] = *(const s16x8*)(gB[i] + k0 + 32);
    }

    frag_t af[NI], bf[4];
#pragma unroll
    for (int i = 0; i < NI; i++) af[i] = *(const frag_t*)&Al[offA[i]];
#pragma unroll
    for (int j = 0; j < 4; j++)  bf[j] = *(const frag_t*)&Bl[offB[j]];
#pragma unroll
    for (int i = 0; i < NI; i++)
#pragma unroll
      for (int j = 0; j < 4; j++)
        acc[i][j] = mfma_16x16x32_bf16(af[i], bf[j], acc[i][j]);
  }

  // epilogue: C/D layout col=lane&15, row=quad*4+reg (verified m89/m91)
#pragma unroll
  for (int j = 0; j < 4; j++) {
    const int col = n0 + wn + j * 16 + l15;
    const float bv = bias[col];
#pragma unroll
    for (int i = 0; i < NI; i++) {
      const int row = m0 + wm + i * 16 + quad * 4;
      if (QKV && z == 2) {
        const int bb = row >> 11, s = row & 2047;
        const int hh = col >> 6,  dd = col & 63;
        u16x4 pk = {f2b(acc[i][j][0] + bv), f2b(acc[i][j][1] + bv),
                    f2b(acc[i][j][2] + bv), f2b(acc[i][j][3] + bv)};
        *(u16x4*)((uint16_t*)Cout +
                  (((size_t)bb * NH + hh) * DH + dd) * SEQ + s) = pk;
      } else {
#pragma unroll
        for (int r = 0; r < 4; r++) {
          const float val = (acc[i][j][r] + bv) * sc;
          if (F32OUT)
            ((float*)Cout)[(size_t)(row + r) * DM + col] = val;
          else
            ((uint16_t*)Cout)[(size_t)(row + r) * DM + col] = f2b(val);
        }
      }
    }
  }
}

// ---------------- MFMA flash attention, causal, balanced pairs ----------------
// Fixed-max softmax: s = (q*log2e/32)·k has |s| < ~2.2 => P = exp2(s) safe;
// row-sum l accumulates per-lane, single cross-lane reduction per q-tile.
// Block = one (b,h) x a PAIR of 64-row q-tiles {pr, 31-pr} => every block
// runs exactly 33 k-tile iterations (static balance; grid 512 = 2/CU).
// K/V staged in LDS; register-prefetch double-buffer.
__global__ __launch_bounds__(256) void attn_mfma(
    const uint16_t* __restrict__ Q,   // [MR][DM] (pre-scaled by log2e/32)
    const uint16_t* __restrict__ K,   // [MR][DM]
    const uint16_t* __restrict__ Vt,  // [B*NH][DH][SEQ]
    uint16_t* __restrict__ O)         // [MR][DM] (may alias Q)
{
  __shared__ __align__(16) uint16_t Kl[64 * 72];
  __shared__ __align__(16) uint16_t Vl[64 * 72];
  __shared__ __align__(16) uint16_t Pl[4 * 16 * 72];

  const int t = threadIdx.x;
  const int lane = t & 63, wave = t >> 6;
  const int l15 = lane & 15, quad = lane >> 4;
  const int pr = blockIdx.x >> 5;       // 0..15
  const int bh = blockIdx.x & 31;
  const int b = bh >> 4, h = bh & 15;

  const uint16_t* Kg = K  + (size_t)(b * SEQ) * DM + h * DH;
  const uint16_t* Vg = Vt + (size_t)bh * DH * SEQ;
  uint16_t* Pw = Pl + wave * 16 * 72;
  const int kr = t >> 2, cp = (t & 3) * 16;   // staging slot per thread

  for (int phase = 0; phase < 2; phase++) {
    const int qt = phase == 0 ? pr : 31 - pr;
    const int q0 = qt * 64;
    const int nkt = qt + 1;

    frag_t qf[2];
    const uint16_t* qbase =
        Q + (size_t)(b * SEQ + q0 + wave * 16) * DM + h * DH;
#pragma unroll
    for (int ks = 0; ks < 2; ks++)
      qf[ks] = *(const frag_t*)(qbase + (size_t)l15 * DM + ks * 32 + quad * 8);

    f32x4 Oacc[4];
#pragma unroll
    for (int dt = 0; dt < 4; dt++) Oacc[dt] = {0.f, 0.f, 0.f, 0.f};
    float lsum[4] = {0.f, 0.f, 0.f, 0.f};

    s16x8 kreg0, kreg1, vreg0, vreg1;
    {
      const uint16_t* kg = Kg + (size_t)kr * DM + cp;
      kreg0 = *(const s16x8*)(kg);
      kreg1 = *(const s16x8*)(kg + 8);
      const uint16_t* vg = Vg + (size_t)kr * SEQ + cp;
      vreg0 = *(const s16x8*)(vg);
      vreg1 = *(const s16x8*)(vg + 8);
    }

    for (int kt = 0; kt < nkt; kt++) {
      __syncthreads();
      *(s16x8*)&Kl[kr * 72 + cp]     = kreg0;
      *(s16x8*)&Kl[kr * 72 + cp + 8] = kreg1;
      *(s16x8*)&Vl[kr * 72 + cp]     = vreg0;
      *(s16x8*)&Vl[kr * 72 + cp + 8] = vreg1;
      __syncthreads();

      if (kt + 1 < nkt) {
        const uint16_t* kg = Kg + (size_t)((kt + 1) * 64 + kr) * DM + cp;
        kreg0 = *(const s16x8*)(kg);
        kreg1 = *(const s16x8*)(kg + 8);
        const uint16_t* vg = Vg + (size_t)kr * SEQ + (kt + 1) * 64 + cp;
        vreg0 = *(const s16x8*)(vg);
        vreg1 = *(const s16x8*)(vg + 8);
      }

      // ---- S = Q K^T ----
      f32x4 S[4];
#pragma unroll
      for (int nt = 0; nt < 4; nt++) S[nt] = {0.f, 0.f, 0.f, 0.f};
#pragma unroll
      for (int ks = 0; ks < 2; ks++) {
        frag_t bf[4];
#pragma unroll
        for (int nt = 0; nt < 4; nt++)
          bf[nt] = *(const frag_t*)&Kl[(nt * 16 + l15) * 72 + ks * 32 + quad * 8];
#pragma unroll
        for (int nt = 0; nt < 4; nt++)
          S[nt] = mfma_16x16x32_bf16(qf[ks], bf[nt], S[nt]);
      }

      // ---- P = exp2(S) (causal-masked -> 0), row-sum in regs ----
      const bool diag = (kt == qt);
#pragma unroll
      for (int r = 0; r < 4; r++) {
        const int row = q0 + wave * 16 + quad * 4 + r;
#pragma unroll
        for (int nt = 0; nt < 4; nt++) {
          const int col = kt * 64 + nt * 16 + l15;
          float p = exp2f(S[nt][r]);
          if (diag && col > row) p = 0.f;
          lsum[r] += p;
          Pw[(quad * 4 + r) * 72 + nt * 16 + l15] = f2b(p);
        }
      }

      // ---- O += P V ----
#pragma unroll
      for (int ks = 0; ks < 2; ks++) {
        frag_t pf = *(const frag_t*)&Pw[l15 * 72 + ks * 32 + quad * 8];
        frag_t vf[4];
#pragma unroll
        for (int dt = 0; dt < 4; dt++)
          vf[dt] = *(const frag_t*)&Vl[(dt * 16 + l15) * 72 + ks * 32 + quad * 8];
#pragma unroll
        for (int dt = 0; dt < 4; dt++)
          Oacc[dt] = mfma_16x16x32_bf16(pf, vf[dt], Oacc[dt]);
      }
    }

    float linv[4];
#pragma unroll
    for (int r = 0; r < 4; r++) {
      float l = lsum[r];
      l += __shfl_xor(l, 1);
      l += __shfl_xor(l, 2);
      l += __shfl_xor(l, 4);
      l += __shfl_xor(l, 8);
      linv[r] = 1.f / l;
    }

    uint16_t* obase =
        O + (size_t)(b * SEQ + q0 + wave * 16) * DM + h * DH;
#pragma unroll
    for (int r = 0; r < 4; r++) {
      const int row = quad * 4 + r;
#pragma unroll
      for (int dt = 0; dt < 4; dt++)
        obase[(size_t)row * DM + dt * 16 + l15] = f2b(Oacc[dt][r] * linv[r]);
    }
  }
}

// ---------------- launch ----------------
// ws: WT (8 MB) + Qb (8 MB) + Kb (8 MB) = 24 MB.
// d_out (16 MiB fp32) double-duty: first 8 MiB = V^T (bf16), second 8 MiB =
// xb (bf16 x). Both dead before the final projection overwrites all of d_out.
// Attention output aliases Qb.
extern "C" void kernel_launch(void* const* d_in, const int* in_sizes, int n_in,
                              void* d_out, int out_size, void* d_ws, size_t ws_size,
                              hipStream_t stream) {
  const float* x  = (const float*)d_in[0];
  const float* Wq = (const float*)d_in[1];
  const float* bq = (const float*)d_in[2];
  const float* Wk = (const float*)d_in[3];
  const float* bk = (const float*)d_in[4];
  const float* Wv = (const float*)d_in[5];
  const float* bv = (const float*)d_in[6];
  const float* Wo = (const float*)d_in[7];
  const float* bo = (const float*)d_in[8];

  uint16_t* WT = (uint16_t*)d_ws;
  uint16_t* Qb = WT + (size_t)4 * DM * DM;
  uint16_t* Kb = Qb + (size_t)MR * DM;
  uint16_t* Vtb = (uint16_t*)d_out;                   // V^T [B*NH][DH][SEQ]
  uint16_t* xb  = (uint16_t*)d_out + (size_t)MR * DM; // bf16 x, upper 8 MiB

  prep_all<<<dim3(1024 + MR * DM / 2048), 256, 0, stream>>>(
      Wq, Wk, Wv, Wo, WT, x, xb);
  gemm_bt<128, false, true><<<dim3(8, 32, 3), 256, 0, stream>>>(
      xb, WT, bq, bk, bv, Qb, Kb, Vtb);
  attn_mfma<<<dim3(512), 256, 0, stream>>>(Qb, Kb, Vtb, Qb);
  gemm_bt<64, true, false><<<dim3(8, 64, 1), 256, 0, stream>>>(
      Qb, WT + (size_t)3 * DM * DM, bo, bo, bo, d_out, d_out, d_out);
}